// Round 2
// baseline (554.196 us; speedup 1.0000x reference)
//
#include <hip/hip_runtime.h>

typedef unsigned short ushort_t;
typedef __attribute__((ext_vector_type(8))) short short8;
typedef __attribute__((ext_vector_type(4))) float f32x4;

#define BB 512
#define TT 2048
#define DD 64

__device__ __forceinline__ ushort_t f2b(float f) {
    union { float f; unsigned int i; } v; v.f = f;
    unsigned int u = v.i;
    unsigned int r = (u + 0x7fffu + ((u >> 16) & 1u)) >> 16;
    return (ushort_t)r;
}

// ---------------- Kernel 1: u_repr = mean over T, bf16 copy of lat, fused b_j ----------------
__global__ __launch_bounds__(1024) void k_umean(const float* __restrict__ lat,
                                                const float* __restrict__ Wu,
                                                const float* __restrict__ Ws,
                                                float* __restrict__ u,
                                                float* __restrict__ bj,
                                                ushort_t* __restrict__ latb) {
    int b = blockIdx.x;
    int tid = threadIdx.x;
    int cg = tid & 15;       // col group (float4)
    int rs = tid >> 4;       // row slot in [0,64)
    const float* base = lat + (size_t)b * TT * DD;
    ushort_t* bbase = latb + (size_t)b * TT * DD;
    float acc[4] = {0.f, 0.f, 0.f, 0.f};
#pragma unroll 4
    for (int k = 0; k < 32; k++) {
        int r = rs + 64 * k;
        float4 vv = *reinterpret_cast<const float4*>(base + (size_t)r * DD + cg * 4);
        acc[0] += vv.x; acc[1] += vv.y; acc[2] += vv.z; acc[3] += vv.w;
        ushort4 sv;
        sv.x = f2b(vv.x); sv.y = f2b(vv.y); sv.z = f2b(vv.z); sv.w = f2b(vv.w);
        *reinterpret_cast<ushort4*>(bbase + (size_t)r * DD + cg * 4) = sv;
    }
    __shared__ float sm[64][64];
#pragma unroll
    for (int j = 0; j < 4; j++) sm[rs][cg * 4 + j] = acc[j];
    __syncthreads();
    {
        int col = tid & 63, g = tid >> 6;   // g in [0,16)
        float p = 0.0f;
#pragma unroll
        for (int k = 0; k < 4; k++) p += sm[g + 16 * k][col];
        sm[g][col] = p;  // rows <16 are read only by their own writer thread
    }
    __syncthreads();
    if (tid < 64) {
        float tot = 0.0f;
#pragma unroll
        for (int g = 0; g < 16; g++) tot += sm[g][tid];
        float um = tot * (1.0f / (float)TT);
        u[(size_t)b * DD + tid] = um;
        // fused logit: v[d] = sum_h Wu[d][h]*Ws[32+h]; bj[b] = sum_d u[d]*v[d]
        float vv = 0.0f;
#pragma unroll
        for (int h = 0; h < 32; h++) vv += Wu[tid * 32 + h] * Ws[32 + h];
        float p = um * vv;
#pragma unroll
        for (int m = 1; m < 64; m <<= 1) p += __shfl_xor(p, m, 64);
        if (tid == 0) bj[b] = p;
    }
}

// ---------------- Kernel 2: softmax stats (inline) + level partition -> cross -> cbias ----------------
__global__ __launch_bounds__(256) void k_levels(const float* __restrict__ u,
                                                const float* __restrict__ bj,
                                                const float* __restrict__ lw,
                                                const float* __restrict__ Wf,
                                                const float* __restrict__ bfv,
                                                float* __restrict__ cbias) {
    int i = blockIdx.x;
    int tid = threadIdx.x;
    int lane = tid & 63, wv = tid >> 6;
    __shared__ signed char lvl[512];
    __shared__ float redf[16];
    __shared__ int redi[8];
    __shared__ __align__(16) float lr[16][3][64];
    __shared__ float crossS[64];

    int jA = tid, jB = tid + 256;
    float vA = bj[jA], vB = bj[jB];

    // ---- stats round 1: global max + argmax (first-index tie-break)
    float mx; int mi;
    if (vB > vA) { mx = vB; mi = jB; } else { mx = vA; mi = jA; }
#pragma unroll
    for (int m = 1; m < 64; m <<= 1) {
        float om = __shfl_xor(mx, m, 64);
        int oi = __shfl_xor(mi, m, 64);
        if (om > mx || (om == mx && oi < mi)) { mx = om; mi = oi; }
    }
    if (lane == 0) { redf[wv] = mx; redi[wv] = mi; }
    __syncthreads();
    float maxb = redf[0]; int j1 = redi[0];
#pragma unroll
    for (int w2 = 1; w2 < 4; w2++) {
        float om = redf[w2]; int oi = redi[w2];
        if (om > maxb || (om == maxb && oi < j1)) { maxb = om; j1 = oi; }
    }

    // ---- stats round 2: 2nd argmax (exclude j1) + Z
    float eA = expf(vA - maxb), eB = expf(vB - maxb);
    float zs = eA + eB;
    float mx2; int mi2;
    {
        float tA = (jA == j1) ? -3.4e38f : vA;
        float tB = (jB == j1) ? -3.4e38f : vB;
        if (tB > tA) { mx2 = tB; mi2 = jB; } else { mx2 = tA; mi2 = jA; }
    }
#pragma unroll
    for (int m = 1; m < 64; m <<= 1) {
        float om = __shfl_xor(mx2, m, 64);
        int oi = __shfl_xor(mi2, m, 64);
        if (om > mx2 || (om == mx2 && oi < mi2)) { mx2 = om; mi2 = oi; }
        zs += __shfl_xor(zs, m, 64);
    }
    if (lane == 0) { redf[4 + wv] = mx2; redi[4 + wv] = mi2; redf[8 + wv] = zs; }
    __syncthreads();
    float Z = redf[8] + redf[9] + redf[10] + redf[11];
    int j2 = redi[4]; float m2v = redf[4];
#pragma unroll
    for (int w2 = 1; w2 < 4; w2++) {
        float om = redf[4 + w2]; int oi = redi[4 + w2];
        if (om > m2v || (om == m2v && oi < j2)) { m2v = om; j2 = oi; }
    }

    float Ei = expf(bj[i] - maxb);
    float denom = Z - Ei;
    float wA = (jA == i) ? 0.0f : (eA / denom);
    float wB = (jB == i) ? 0.0f : (eB / denom);

    // ---- phase 1: sum of w -> mean0
    float s = wA + wB;
#pragma unroll
    for (int m = 1; m < 64; m <<= 1) s += __shfl_xor(s, m, 64);
    if (lane == 0) redf[wv] = s;
    __syncthreads();
    float mean0 = (redf[0] + redf[1] + redf[2] + redf[3]) * (1.0f / 511.0f);

    // ---- phase 2: level-0 partition stats (active-sum, active-count, lower-count)
    float pa = 0.0f, ca = 0.0f, c1 = 0.0f;
    if (jA != i) { if (wA <= mean0) c1 += 1.0f; else { pa += wA; ca += 1.0f; } }
    if (jB != i) { if (wB <= mean0) c1 += 1.0f; else { pa += wB; ca += 1.0f; } }
#pragma unroll
    for (int m = 1; m < 64; m <<= 1) {
        pa += __shfl_xor(pa, m, 64);
        ca += __shfl_xor(ca, m, 64);
        c1 += __shfl_xor(c1, m, 64);
    }
    if (lane == 0) { redf[4 + wv] = pa; redf[8 + wv] = ca; redf[12 + wv] = c1; }
    __syncthreads();
    float asum1 = redf[4] + redf[5] + redf[6] + redf[7];
    float cact  = redf[8] + redf[9] + redf[10] + redf[11];
    float cnt1  = redf[12] + redf[13] + redf[14] + redf[15];
    float mean1 = asum1 / fmaxf(cact, 1.0f);

    // ---- phase 3: level assignment + level-2 count
    float c2 = 0.0f;
    signed char lA, lB;
    if (jA == i) lA = -1;
    else if (wA <= mean0) lA = 0;
    else if (wA <= mean1) { lA = 1; c2 += 1.0f; }
    else lA = 2;
    if (jB == i) lB = -1;
    else if (wB <= mean0) lB = 0;
    else if (wB <= mean1) { lB = 1; c2 += 1.0f; }
    else lB = 2;
    lvl[jA] = lA; lvl[jB] = lB;
#pragma unroll
    for (int m = 1; m < 64; m <<= 1) c2 += __shfl_xor(c2, m, 64);
    if (lane == 0) redf[wv] = c2;
    __syncthreads();
    float cnt2 = redf[0] + redf[1] + redf[2] + redf[3];
    float cnt3 = cact - cnt2;

    // ---- gather: 16 j-groups x 16 col-threads, float4 loads
    int jg = tid >> 4;
    int d4 = (tid & 15) << 2;
    float4 a0 = make_float4(0.f, 0.f, 0.f, 0.f);
    float4 a1 = make_float4(0.f, 0.f, 0.f, 0.f);
    float4 a2 = make_float4(0.f, 0.f, 0.f, 0.f);
#pragma unroll 8
    for (int j = jg; j < 512; j += 16) {
        int l = lvl[j];
        float4 uv = *reinterpret_cast<const float4*>(u + (size_t)j * DD + d4);
        if (l == 0) { a0.x += uv.x; a0.y += uv.y; a0.z += uv.z; a0.w += uv.w; }
        else if (l == 1) { a1.x += uv.x; a1.y += uv.y; a1.z += uv.z; a1.w += uv.w; }
        else if (l == 2) { a2.x += uv.x; a2.y += uv.y; a2.z += uv.z; a2.w += uv.w; }
    }
    *reinterpret_cast<float4*>(&lr[jg][0][d4]) = a0;
    *reinterpret_cast<float4*>(&lr[jg][1][d4]) = a1;
    *reinterpret_cast<float4*>(&lr[jg][2][d4]) = a2;
    __syncthreads();

    if (tid < 64) {
        float s0 = 0.0f, s1 = 0.0f, s2 = 0.0f;
#pragma unroll
        for (int g2 = 0; g2 < 16; g2++) {
            s0 += lr[g2][0][tid];
            s1 += lr[g2][1][tid];
            s2 += lr[g2][2][tid];
        }
        int fb = (j1 == i) ? j2 : j1;
        float L1 = (cnt1 > 0.0f) ? s0 / cnt1 : 0.0f;
        float L2 = (cnt2 > 0.0f) ? s1 / cnt2 : 0.0f;
        float L3 = (cnt3 > 0.0f) ? s2 / cnt3 : u[(size_t)fb * DD + tid];
        crossS[tid] = lw[0] * L1 + lw[1] * L2 + lw[2] * L3;
    }
    __syncthreads();
    if (tid < 64) {
        int n = tid;
        float sacc = 0.0f;
        for (int dd = 0; dd < 64; dd++) sacc += crossS[dd] * Wf[(64 + dd) * 64 + n];
        cbias[(size_t)i * DD + n] = sacc + bfv[n];
    }
}

// ---------------- Kernel 3: out = LN(latb @ bf16(Wf_top + I) + cbias[b]) ----------------
__global__ __launch_bounds__(256) void k_fused(const ushort_t* __restrict__ latb,
                                               const float* __restrict__ Wf,
                                               const float* __restrict__ cbias,
                                               const float* __restrict__ gamma,
                                               const float* __restrict__ beta,
                                               float* __restrict__ out) {
    int tid = threadIdx.x;
    int lane = tid & 63, wv = tid >> 6;
    int lo = lane & 15, quad = lane >> 4;
    long wid = (long)blockIdx.x * 4 + wv;   // [0, 16384)

    // B fragments of W' = Wf_top + I  (B[k][n], k = 32*s + 8*quad + j, n = 16*c + lo)
    short8 bfr[4][2];
#pragma unroll
    for (int c = 0; c < 4; c++) {
        int n = 16 * c + lo;
#pragma unroll
        for (int s = 0; s < 2; s++) {
            short8 t;
#pragma unroll
            for (int j = 0; j < 8; j++) {
                int k = 32 * s + 8 * quad + j;
                float vv = Wf[k * 64 + n] + (k == n ? 1.0f : 0.0f);
                t[j] = (short)f2b(vv);
            }
            bfr[c][s] = t;
        }
    }
    float ga[4], be[4], cb[4];
    int b = (int)(wid >> 5);  // 32 wids (64 rows each) per batch element
#pragma unroll
    for (int c = 0; c < 4; c++) {
        int n = 16 * c + lo;
        ga[c] = gamma[n];
        be[c] = beta[n];
        cb[c] = cbias[(size_t)b * DD + n];
    }

    for (int t4 = 0; t4 < 4; t4++) {
        long row0 = (wid * 4 + t4) * 16;
        const ushort_t* ap = latb + (size_t)(row0 + lo) * DD + quad * 8;
        short8 a0 = *reinterpret_cast<const short8*>(ap);
        short8 a1 = *reinterpret_cast<const short8*>(ap + 32);

        f32x4 acc[4];
#pragma unroll
        for (int c = 0; c < 4; c++) { acc[c] = (f32x4){0.f, 0.f, 0.f, 0.f}; }
#pragma unroll
        for (int c = 0; c < 4; c++) {
            acc[c] = __builtin_amdgcn_mfma_f32_16x16x32_bf16(a0, bfr[c][0], acc[c], 0, 0, 0);
            acc[c] = __builtin_amdgcn_mfma_f32_16x16x32_bf16(a1, bfr[c][1], acc[c], 0, 0, 0);
        }
        float y[4][4];
#pragma unroll
        for (int c = 0; c < 4; c++)
#pragma unroll
            for (int r = 0; r < 4; r++) y[c][r] = acc[c][r] + cb[c];
#pragma unroll
        for (int r = 0; r < 4; r++) {
            float s = y[0][r] + y[1][r] + y[2][r] + y[3][r];
            float q = y[0][r] * y[0][r] + y[1][r] * y[1][r] + y[2][r] * y[2][r] + y[3][r] * y[3][r];
#pragma unroll
            for (int m = 1; m < 16; m <<= 1) {
                s += __shfl_xor(s, m, 64);
                q += __shfl_xor(q, m, 64);
            }
            float mean = s * (1.0f / 64.0f);
            float var = q * (1.0f / 64.0f) - mean * mean;
            float rstd = rsqrtf(var + 1e-5f);
            long row = row0 + quad * 4 + r;
#pragma unroll
            for (int c = 0; c < 4; c++) {
                float o = ga[c] * (y[c][r] - mean) * rstd + be[c];
                out[(size_t)row * DD + 16 * c + lo] = o;
            }
        }
    }
}

extern "C" void kernel_launch(void* const* d_in, const int* in_sizes, int n_in,
                              void* d_out, int out_size, void* d_ws, size_t ws_size,
                              hipStream_t stream) {
    const float* lat   = (const float*)d_in[0];
    // d_in[1]=Wx, d_in[2]=bx, d_in[6]=bs: dead (cancel in softmax/argmax)
    const float* Wu    = (const float*)d_in[3];
    // d_in[4]=bu: dead (constant shift in b_j cancels)
    const float* Ws    = (const float*)d_in[5];
    const float* lw    = (const float*)d_in[7];
    const float* Wf    = (const float*)d_in[8];
    const float* bfv   = (const float*)d_in[9];
    const float* gamma = (const float*)d_in[10];
    const float* beta  = (const float*)d_in[11];
    float* out = (float*)d_out;

    char* ws = (char*)d_ws;
    float*    u     = (float*)(ws);                  // 512*64*4 = 131072 B
    float*    bjv   = (float*)(ws + 131072);         // 2048 B
    float*    cbias = (float*)(ws + 133120);         // 131072 B
    ushort_t* latb  = (ushort_t*)(ws + 264192);      // 512*2048*64*2 = 134217728 B

    k_umean<<<BB, 1024, 0, stream>>>(lat, Wu, Ws, u, bjv, latb);
    k_levels<<<BB, 256, 0, stream>>>(u, bjv, lw, Wf, bfv, cbias);
    k_fused<<<4096, 256, 0, stream>>>(latb, Wf, cbias, gamma, beta, out);
}

// Round 3
// 523.956 us; speedup vs baseline: 1.0577x; 1.0577x over previous
//
#include <hip/hip_runtime.h>

typedef unsigned short ushort_t;
typedef __attribute__((ext_vector_type(8))) short short8;
typedef __attribute__((ext_vector_type(4))) float f32x4;

#define BB 512
#define TT 2048
#define DD 64

__device__ __forceinline__ ushort_t f2b(float f) {
    union { float f; unsigned int i; } v; v.f = f;
    unsigned int u = v.i;
    unsigned int r = (u + 0x7fffu + ((u >> 16) & 1u)) >> 16;
    return (ushort_t)r;
}

// ---------------- Kernel 1: u_repr = mean over T of latent, fused b_j = u . (Wu @ Ws[H:]) ----------------
__global__ __launch_bounds__(1024) void k_umean(const float* __restrict__ lat,
                                                const float* __restrict__ Wu,
                                                const float* __restrict__ Ws,
                                                float* __restrict__ u,
                                                float* __restrict__ bj) {
    int b = blockIdx.x;
    int tid = threadIdx.x;
    int cg = tid & 15;       // col group (float4)
    int rs = tid >> 4;       // row slot in [0,64)
    const float* base = lat + (size_t)b * TT * DD;
    float acc[4] = {0.f, 0.f, 0.f, 0.f};
#pragma unroll 4
    for (int k = 0; k < 32; k++) {
        int r = rs + 64 * k;
        float4 vv = *reinterpret_cast<const float4*>(base + (size_t)r * DD + cg * 4);
        acc[0] += vv.x; acc[1] += vv.y; acc[2] += vv.z; acc[3] += vv.w;
    }
    __shared__ float sm[64][64];
#pragma unroll
    for (int j = 0; j < 4; j++) sm[rs][cg * 4 + j] = acc[j];
    __syncthreads();
    {
        int col = tid & 63, g = tid >> 6;   // g in [0,16)
        float p = 0.0f;
#pragma unroll
        for (int k = 0; k < 4; k++) p += sm[g + 16 * k][col];
        sm[g][col] = p;  // rows <16 are read only by their own writer thread
    }
    __syncthreads();
    if (tid < 64) {
        float tot = 0.0f;
#pragma unroll
        for (int g = 0; g < 16; g++) tot += sm[g][tid];
        float um = tot * (1.0f / (float)TT);
        u[(size_t)b * DD + tid] = um;
        // fused logit: v[d] = sum_h Wu[d][h]*Ws[32+h]; bj[b] = sum_d u[d]*v[d]
        float vv = 0.0f;
#pragma unroll
        for (int h = 0; h < 32; h++) vv += Wu[tid * 32 + h] * Ws[32 + h];
        float p = um * vv;
#pragma unroll
        for (int m = 1; m < 64; m <<= 1) p += __shfl_xor(p, m, 64);
        if (tid == 0) bj[b] = p;
    }
}

// ---------------- Kernel 2: softmax stats (inline) + level partition -> cross -> cbias ----------------
__global__ __launch_bounds__(256) void k_levels(const float* __restrict__ u,
                                                const float* __restrict__ bj,
                                                const float* __restrict__ lw,
                                                const float* __restrict__ Wf,
                                                const float* __restrict__ bfv,
                                                float* __restrict__ cbias) {
    int i = blockIdx.x;
    int tid = threadIdx.x;
    int lane = tid & 63, wv = tid >> 6;
    __shared__ signed char lvl[512];
    __shared__ float redf[16];
    __shared__ int redi[8];
    __shared__ __align__(16) float lr[16][3][64];
    __shared__ float crossS[64];

    int jA = tid, jB = tid + 256;
    float vA = bj[jA], vB = bj[jB];

    // ---- stats round 1: global max + argmax (first-index tie-break)
    float mx; int mi;
    if (vB > vA) { mx = vB; mi = jB; } else { mx = vA; mi = jA; }
#pragma unroll
    for (int m = 1; m < 64; m <<= 1) {
        float om = __shfl_xor(mx, m, 64);
        int oi = __shfl_xor(mi, m, 64);
        if (om > mx || (om == mx && oi < mi)) { mx = om; mi = oi; }
    }
    if (lane == 0) { redf[wv] = mx; redi[wv] = mi; }
    __syncthreads();
    float maxb = redf[0]; int j1 = redi[0];
#pragma unroll
    for (int w2 = 1; w2 < 4; w2++) {
        float om = redf[w2]; int oi = redi[w2];
        if (om > maxb || (om == maxb && oi < j1)) { maxb = om; j1 = oi; }
    }

    // ---- stats round 2: 2nd argmax (exclude j1) + Z
    float eA = expf(vA - maxb), eB = expf(vB - maxb);
    float zs = eA + eB;
    float mx2; int mi2;
    {
        float tA = (jA == j1) ? -3.4e38f : vA;
        float tB = (jB == j1) ? -3.4e38f : vB;
        if (tB > tA) { mx2 = tB; mi2 = jB; } else { mx2 = tA; mi2 = jA; }
    }
#pragma unroll
    for (int m = 1; m < 64; m <<= 1) {
        float om = __shfl_xor(mx2, m, 64);
        int oi = __shfl_xor(mi2, m, 64);
        if (om > mx2 || (om == mx2 && oi < mi2)) { mx2 = om; mi2 = oi; }
        zs += __shfl_xor(zs, m, 64);
    }
    if (lane == 0) { redf[4 + wv] = mx2; redi[4 + wv] = mi2; redf[8 + wv] = zs; }
    __syncthreads();
    float Z = redf[8] + redf[9] + redf[10] + redf[11];
    int j2 = redi[4]; float m2v = redf[4];
#pragma unroll
    for (int w2 = 1; w2 < 4; w2++) {
        float om = redf[4 + w2]; int oi = redi[4 + w2];
        if (om > m2v || (om == m2v && oi < j2)) { m2v = om; j2 = oi; }
    }

    float Ei = expf(bj[i] - maxb);
    float denom = Z - Ei;
    float wA = (jA == i) ? 0.0f : (eA / denom);
    float wB = (jB == i) ? 0.0f : (eB / denom);

    // ---- phase 1: sum of w -> mean0
    float s = wA + wB;
#pragma unroll
    for (int m = 1; m < 64; m <<= 1) s += __shfl_xor(s, m, 64);
    if (lane == 0) redf[wv] = s;
    __syncthreads();
    float mean0 = (redf[0] + redf[1] + redf[2] + redf[3]) * (1.0f / 511.0f);

    // ---- phase 2: level-0 partition stats (active-sum, active-count, lower-count)
    float pa = 0.0f, ca = 0.0f, c1 = 0.0f;
    if (jA != i) { if (wA <= mean0) c1 += 1.0f; else { pa += wA; ca += 1.0f; } }
    if (jB != i) { if (wB <= mean0) c1 += 1.0f; else { pa += wB; ca += 1.0f; } }
#pragma unroll
    for (int m = 1; m < 64; m <<= 1) {
        pa += __shfl_xor(pa, m, 64);
        ca += __shfl_xor(ca, m, 64);
        c1 += __shfl_xor(c1, m, 64);
    }
    if (lane == 0) { redf[4 + wv] = pa; redf[8 + wv] = ca; redf[12 + wv] = c1; }
    __syncthreads();
    float asum1 = redf[4] + redf[5] + redf[6] + redf[7];
    float cact  = redf[8] + redf[9] + redf[10] + redf[11];
    float cnt1  = redf[12] + redf[13] + redf[14] + redf[15];
    float mean1 = asum1 / fmaxf(cact, 1.0f);

    // ---- phase 3: level assignment + level-2 count
    float c2 = 0.0f;
    signed char lA, lB;
    if (jA == i) lA = -1;
    else if (wA <= mean0) lA = 0;
    else if (wA <= mean1) { lA = 1; c2 += 1.0f; }
    else lA = 2;
    if (jB == i) lB = -1;
    else if (wB <= mean0) lB = 0;
    else if (wB <= mean1) { lB = 1; c2 += 1.0f; }
    else lB = 2;
    lvl[jA] = lA; lvl[jB] = lB;
#pragma unroll
    for (int m = 1; m < 64; m <<= 1) c2 += __shfl_xor(c2, m, 64);
    if (lane == 0) redf[wv] = c2;
    __syncthreads();
    float cnt2 = redf[0] + redf[1] + redf[2] + redf[3];
    float cnt3 = cact - cnt2;

    // ---- gather: 16 j-groups x 16 col-threads, float4 loads
    int jg = tid >> 4;
    int d4 = (tid & 15) << 2;
    float4 a0 = make_float4(0.f, 0.f, 0.f, 0.f);
    float4 a1 = make_float4(0.f, 0.f, 0.f, 0.f);
    float4 a2 = make_float4(0.f, 0.f, 0.f, 0.f);
#pragma unroll 8
    for (int j = jg; j < 512; j += 16) {
        int l = lvl[j];
        float4 uv = *reinterpret_cast<const float4*>(u + (size_t)j * DD + d4);
        if (l == 0) { a0.x += uv.x; a0.y += uv.y; a0.z += uv.z; a0.w += uv.w; }
        else if (l == 1) { a1.x += uv.x; a1.y += uv.y; a1.z += uv.z; a1.w += uv.w; }
        else if (l == 2) { a2.x += uv.x; a2.y += uv.y; a2.z += uv.z; a2.w += uv.w; }
    }
    *reinterpret_cast<float4*>(&lr[jg][0][d4]) = a0;
    *reinterpret_cast<float4*>(&lr[jg][1][d4]) = a1;
    *reinterpret_cast<float4*>(&lr[jg][2][d4]) = a2;
    __syncthreads();

    if (tid < 64) {
        float s0 = 0.0f, s1 = 0.0f, s2 = 0.0f;
#pragma unroll
        for (int g2 = 0; g2 < 16; g2++) {
            s0 += lr[g2][0][tid];
            s1 += lr[g2][1][tid];
            s2 += lr[g2][2][tid];
        }
        int fb = (j1 == i) ? j2 : j1;
        float L1 = (cnt1 > 0.0f) ? s0 / cnt1 : 0.0f;
        float L2 = (cnt2 > 0.0f) ? s1 / cnt2 : 0.0f;
        float L3 = (cnt3 > 0.0f) ? s2 / cnt3 : u[(size_t)fb * DD + tid];
        crossS[tid] = lw[0] * L1 + lw[1] * L2 + lw[2] * L3;
    }
    __syncthreads();
    if (tid < 64) {
        int n = tid;
        float sacc = 0.0f;
        for (int dd = 0; dd < 64; dd++) sacc += crossS[dd] * Wf[(64 + dd) * 64 + n];
        cbias[(size_t)i * DD + n] = sacc + bfv[n];
    }
}

// ---------------- Kernel 3: out = LN(lat @ bf16(Wf_top + I) + cbias[b]) ----------------
// Reverse-order consumption: k_umean streamed lat forward, so L3 holds the TAIL of lat.
// Read b=511 first and walk backward; nontemporal out-stores avoid evicting lat from L3.
__global__ __launch_bounds__(256) void k_fused(const float* __restrict__ lat,
                                               const float* __restrict__ Wf,
                                               const float* __restrict__ cbias,
                                               const float* __restrict__ gamma,
                                               const float* __restrict__ beta,
                                               float* __restrict__ out) {
    int tid = threadIdx.x;
    int lane = tid & 63, wv = tid >> 6;
    int lo = lane & 15, quad = lane >> 4;
    long wid = 16383 - ((long)blockIdx.x * 4 + wv);   // reversed: [16383, 0]

    // B fragments of W' = Wf_top + I  (B[k][n], k = 32*s + 8*quad + j, n = 16*c + lo)
    short8 bfr[4][2];
#pragma unroll
    for (int c = 0; c < 4; c++) {
        int n = 16 * c + lo;
#pragma unroll
        for (int s = 0; s < 2; s++) {
            short8 t;
#pragma unroll
            for (int j = 0; j < 8; j++) {
                int k = 32 * s + 8 * quad + j;
                float vv = Wf[k * 64 + n] + (k == n ? 1.0f : 0.0f);
                t[j] = (short)f2b(vv);
            }
            bfr[c][s] = t;
        }
    }
    float ga[4], be[4], cb[4];
    int b = (int)(wid >> 5);  // 32 wids (64 rows each) per batch element
#pragma unroll
    for (int c = 0; c < 4; c++) {
        int n = 16 * c + lo;
        ga[c] = gamma[n];
        be[c] = beta[n];
        cb[c] = cbias[(size_t)b * DD + n];
    }

    for (int t4 = 0; t4 < 4; t4++) {
        long row0 = (wid * 4 + t4) * 16;
        const float* ap = lat + (size_t)(row0 + lo) * DD + quad * 8;
        float4 f0 = *reinterpret_cast<const float4*>(ap);
        float4 f1 = *reinterpret_cast<const float4*>(ap + 4);
        float4 f2 = *reinterpret_cast<const float4*>(ap + 32);
        float4 f3 = *reinterpret_cast<const float4*>(ap + 36);
        short8 a0, a1;
        a0[0] = (short)f2b(f0.x); a0[1] = (short)f2b(f0.y);
        a0[2] = (short)f2b(f0.z); a0[3] = (short)f2b(f0.w);
        a0[4] = (short)f2b(f1.x); a0[5] = (short)f2b(f1.y);
        a0[6] = (short)f2b(f1.z); a0[7] = (short)f2b(f1.w);
        a1[0] = (short)f2b(f2.x); a1[1] = (short)f2b(f2.y);
        a1[2] = (short)f2b(f2.z); a1[3] = (short)f2b(f2.w);
        a1[4] = (short)f2b(f3.x); a1[5] = (short)f2b(f3.y);
        a1[6] = (short)f2b(f3.z); a1[7] = (short)f2b(f3.w);

        f32x4 acc[4];
#pragma unroll
        for (int c = 0; c < 4; c++) { acc[c] = (f32x4){0.f, 0.f, 0.f, 0.f}; }
#pragma unroll
        for (int c = 0; c < 4; c++) {
            acc[c] = __builtin_amdgcn_mfma_f32_16x16x32_bf16(a0, bfr[c][0], acc[c], 0, 0, 0);
            acc[c] = __builtin_amdgcn_mfma_f32_16x16x32_bf16(a1, bfr[c][1], acc[c], 0, 0, 0);
        }
        float y[4][4];
#pragma unroll
        for (int c = 0; c < 4; c++)
#pragma unroll
            for (int r = 0; r < 4; r++) y[c][r] = acc[c][r] + cb[c];
#pragma unroll
        for (int r = 0; r < 4; r++) {
            float s = y[0][r] + y[1][r] + y[2][r] + y[3][r];
            float q = y[0][r] * y[0][r] + y[1][r] * y[1][r] + y[2][r] * y[2][r] + y[3][r] * y[3][r];
#pragma unroll
            for (int m = 1; m < 16; m <<= 1) {
                s += __shfl_xor(s, m, 64);
                q += __shfl_xor(q, m, 64);
            }
            float mean = s * (1.0f / 64.0f);
            float var = q * (1.0f / 64.0f) - mean * mean;
            float rstd = rsqrtf(var + 1e-5f);
            long row = row0 + quad * 4 + r;
#pragma unroll
            for (int c = 0; c < 4; c++) {
                float o = ga[c] * (y[c][r] - mean) * rstd + be[c];
                __builtin_nontemporal_store(o, &out[(size_t)row * DD + 16 * c + lo]);
            }
        }
    }
}

extern "C" void kernel_launch(void* const* d_in, const int* in_sizes, int n_in,
                              void* d_out, int out_size, void* d_ws, size_t ws_size,
                              hipStream_t stream) {
    const float* lat   = (const float*)d_in[0];
    // d_in[1]=Wx, d_in[2]=bx, d_in[6]=bs: dead (cancel in softmax/argmax)
    const float* Wu    = (const float*)d_in[3];
    // d_in[4]=bu: dead (constant shift in b_j cancels)
    const float* Ws    = (const float*)d_in[5];
    const float* lw    = (const float*)d_in[7];
    const float* Wf    = (const float*)d_in[8];
    const float* bfv   = (const float*)d_in[9];
    const float* gamma = (const float*)d_in[10];
    const float* beta  = (const float*)d_in[11];
    float* out = (float*)d_out;

    char* ws = (char*)d_ws;
    float* u     = (float*)(ws);                 // 512*64*4 = 131072 B
    float* bjv   = (float*)(ws + 131072);        // 2048 B
    float* cbias = (float*)(ws + 133120);        // 131072 B

    k_umean<<<BB, 1024, 0, stream>>>(lat, Wu, Ws, u, bjv);
    k_levels<<<BB, 256, 0, stream>>>(u, bjv, lw, Wf, bfv, cbias);
    k_fused<<<4096, 256, 0, stream>>>(lat, Wf, cbias, gamma, beta, out);
}